// Round 9
// baseline (74.832 us; speedup 1.0000x reference)
//
#include <hip/hip_runtime.h>

#define NK 19
#define NB 8
#define NC 256
#define NP 8192           // 64*128
#define NBP (NB*NP)       // 65536

typedef unsigned char u8;
typedef __attribute__((ext_vector_type(8))) short bf16x8;   // 8 bf16 = 4 VGPR
typedef __attribute__((ext_vector_type(4))) float f32x4;    // MFMA C/D

__device__ __forceinline__ short f2bf_rne(float v) {
  unsigned u = __float_as_uint(v);
  unsigned r = u + 0x7fffu + ((u >> 16) & 1u);              // RNE
  return (short)(r >> 16);
}
__device__ __forceinline__ float bf2f(short h) {
  return __uint_as_float(((unsigned)(unsigned short)h) << 16);
}

// ---------------- kernel 1: argmax over classes + integer counts ----------------
__global__ __launch_bounds__(256) void k_argmax(const float* __restrict__ target,
                                                u8* __restrict__ lab,
                                                int* __restrict__ counts) {
  __shared__ float tl[256 * NK];                 // 19456 B
  __shared__ int lcnt[NK];
  if (threadIdx.x < NK) lcnt[threadIdx.x] = 0;
  const float4* src = (const float4*)(target + (size_t)blockIdx.x * (256 * NK));
  float4* dst = (float4*)tl;
  for (int i = threadIdx.x; i < 256 * NK / 4; i += 256) dst[i] = src[i];
  __syncthreads();
  const float* row = &tl[threadIdx.x * NK];
  float best = row[0]; int bk = 0;
#pragma unroll
  for (int k = 1; k < NK; ++k) { float v = row[k]; if (v > best) { best = v; bk = k; } }
  int g = blockIdx.x * 256 + threadIdx.x;
  lab[g] = (u8)bk;
  atomicAdd(&lcnt[bk], 1);
  __syncthreads();
  int b = g >> 13;
  if (threadIdx.x < NK) atomicAdd(&counts[b * NK + threadIdx.x], lcnt[threadIdx.x]);
}

// ---------------- kernel 2: class sums as MFMA GEMM ----------------
// sums[c][k] = sum_p feat[c][p] * onehot[p][k].  A = feat (bf16 hi + lo),
// B = onehot (exact in bf16).  mfma_f32_16x16x32_bf16; A-frag row=lane&15,
// B-frag col=lane&15, shared k(lane,j)=8*(lane>>4)+j (same mapping both sides
// -> k-permutation cancels).  Grid: [2f][8b][2mh][16chunk]; 8 waves/block,
// wave w owns channels mh*128 + w*16 + row; chunk = 512 pixels (16 K-steps).
__global__ __launch_bounds__(512, 2) void k_gemm(const float* __restrict__ fS,
                                                 const float* __restrict__ fT,
                                                 const u8* __restrict__ lab,
                                                 float* __restrict__ gpart) {
  int id = blockIdx.x;                           // [0, 512)
  int chunk = id & 15;
  int mh = (id >> 4) & 1;
  int b  = (id >> 5) & 7;
  int f  = (id >> 8);
  int t = threadIdx.x, wave = t >> 6, lane = t & 63;
  int row = lane & 15, kg = lane >> 4;
  const float* F = (f ? fT : fS) + (size_t)b * NC * NP;
  int c = mh * 128 + wave * 16 + row;
  const float* rp = F + (size_t)c * NP;
  const u8* lb = lab + b * NP;
  int pb = chunk * 512 + kg * 8;                 // this lane's first pixel
  f32x4 acc0 = {0.f, 0.f, 0.f, 0.f};            // classes 0..15
  f32x4 acc1 = {0.f, 0.f, 0.f, 0.f};            // classes 16..18 (+pad)
  // 1-deep register pipeline
  float4 A0 = *(const float4*)(rp + pb);
  float4 A1 = *(const float4*)(rp + pb + 4);
  uint2  L  = *(const uint2*)(lb + pb);
  for (int ks = 0; ks < 16; ++ks) {
    float4 cA0 = A0, cA1 = A1; uint2 cL = L;
    if (ks < 15) {
      int p = pb + (ks + 1) * 32;
      A0 = *(const float4*)(rp + p);
      A1 = *(const float4*)(rp + p + 4);
      L  = *(const uint2*)(lb + p);
    }
    float av[8] = {cA0.x, cA0.y, cA0.z, cA0.w, cA1.x, cA1.y, cA1.z, cA1.w};
    unsigned lw[2] = {cL.x, cL.y};
    bf16x8 ah, al, b0, b1;
#pragma unroll
    for (int j = 0; j < 8; ++j) {
      float v = av[j];
      short h = f2bf_rne(v);
      ah[j] = h;
      al[j] = f2bf_rne(v - bf2f(h));
      int lj = (int)((lw[j >> 2] >> ((j & 3) * 8)) & 255u);
      b0[j] = (lj == row)      ? (short)0x3F80 : (short)0;   // bf16 1.0
      b1[j] = (lj == row + 16) ? (short)0x3F80 : (short)0;   // labels<=18 -> auto-false for row>2
    }
    acc0 = __builtin_amdgcn_mfma_f32_16x16x32_bf16(ah, b0, acc0, 0, 0, 0);
    acc0 = __builtin_amdgcn_mfma_f32_16x16x32_bf16(al, b0, acc0, 0, 0, 0);
    acc1 = __builtin_amdgcn_mfma_f32_16x16x32_bf16(ah, b1, acc1, 0, 0, 0);
    acc1 = __builtin_amdgcn_mfma_f32_16x16x32_bf16(al, b1, acc1, 0, 0, 0);
  }
  // writeback: D lane l holds D[(l>>4)*4 + r][l&15]  (verified C/D layout)
  int fbm = (f * NB + b) * 2 + mh;
  float* out = gpart + ((size_t)fbm * 16 + chunk) * (128 * 19);
  int clocal = wave * 16 + kg * 4;
#pragma unroll
  for (int r = 0; r < 4; ++r) {
    out[(clocal + r) * 19 + row] = acc0[r];
    if (row < 3) out[(clocal + r) * 19 + 16 + row] = acc1[r];
  }
}

// ---------------- kernel 2b: fold the 16 K-chunks ----------------
__global__ __launch_bounds__(256) void k_sumred(const float* __restrict__ gpart,
                                                float* __restrict__ sums) {
  int fbm = blockIdx.x;                          // [0, 32)
  const float* src = gpart + (size_t)fbm * 16 * 2432;
  for (int idx = threadIdx.x; idx < 2432; idx += 256) {
    float s = 0.f;
#pragma unroll
    for (int ch = 0; ch < 16; ++ch) s += src[ch * 2432 + idx];
    sums[(size_t)fbm * 2432 + idx] = s;          // == [f][b][c][k] flat
  }
}

// ---------------- kernel 3: means + per-(f,b,k) center norms ----------------
__global__ __launch_bounds__(256) void k_means(const float* __restrict__ sums,
                                               const int* __restrict__ counts,
                                               float* __restrict__ means,
                                               float* __restrict__ cnorm) {
  int b = blockIdx.x / NK, k = blockIdx.x % NK;
  int c = threadIdx.x;
  float cnt = (float)counts[b * NK + k] + 1e-6f;
  size_t iS = ((size_t)(b * NC + c)) * NK + k;
  size_t iT = ((size_t)((NB + b) * NC + c)) * NK + k;
  float mS = sums[iS] / cnt;
  float mT = sums[iT] / cnt;
  means[iS] = mS;
  means[iT] = mT;
  float sS = mS * mS, sT = mT * mT;
#pragma unroll
  for (int off = 32; off > 0; off >>= 1) { sS += __shfl_down(sS, off, 64); sT += __shfl_down(sT, off, 64); }
  __shared__ float redS[4], redT[4];
  int wid = threadIdx.x >> 6, lane = threadIdx.x & 63;
  if (lane == 0) { redS[wid] = sS; redT[wid] = sT; }
  __syncthreads();
  if (threadIdx.x == 0) {
    float tS = redS[0] + redS[1] + redS[2] + redS[3];
    float tT = redT[0] + redT[1] + redT[2] + redT[3];
    cnorm[b * NK + k]           = fmaxf(sqrtf(tS), 1e-8f);
    cnorm[NB * NK + b * NK + k] = fmaxf(sqrtf(tT), 1e-8f);
  }
}

// ---------------- kernel 4: per-pixel cosine + squared diff (4-way channel split) ----------------
__global__ __launch_bounds__(256) void k_cos(const float* __restrict__ fS,
                                             const float* __restrict__ fT,
                                             const u8* __restrict__ lab,
                                             const float* __restrict__ means,
                                             const float* __restrict__ cnorm,
                                             float* __restrict__ partial) {
  __shared__ float R[1024];
  int b = blockIdx.x >> 7, pt = blockIdx.x & 127;
  int t = threadIdx.x;
  int px = t & 63, cg = t >> 6;
  int p = pt * 64 + px;
  int k = lab[b * NP + p];
  const float* rs = fS + (size_t)b * NC * NP + p;
  const float* rt = fT + (size_t)b * NC * NP + p;
  const float* mSb = means + (size_t)(b * NC) * NK;
  const float* mTb = means + (size_t)((NB + b) * NC) * NK;
  float dS = 0.f, nS = 0.f, dT = 0.f, nT = 0.f;
  int c0 = cg * 64;
#pragma unroll 8
  for (int j = 0; j < 64; ++j) {
    int c = c0 + j;
    float vS = rs[(size_t)c * NP];
    float vT = rt[(size_t)c * NP];
    float cS = mSb[c * NK + k];
    float cT = mTb[c * NK + k];
    dS += vS * cS; nS += vS * vS;
    dT += vT * cT; nT += vT * vT;
  }
  R[t] = dS; R[256 + t] = nS; R[512 + t] = dT; R[768 + t] = nT;
  __syncthreads();
  if (t < 64) {
    dS = R[t]       + R[64 + t]  + R[128 + t] + R[192 + t];
    nS = R[256 + t] + R[320 + t] + R[384 + t] + R[448 + t];
    dT = R[512 + t] + R[576 + t] + R[640 + t] + R[704 + t];
    nT = R[768 + t] + R[832 + t] + R[896 + t] + R[960 + t];
    float cnS = cnorm[b * NK + k];
    float cnT = cnorm[NB * NK + b * NK + k];
    float cosS = dS / (fmaxf(sqrtf(nS), 1e-8f) * cnS);
    float cosT = dT / (fmaxf(sqrtf(nT), 1e-8f) * cnT);
    float d = cosS - cosT;
    float v = d * d;
#pragma unroll
    for (int off = 32; off > 0; off >>= 1) v += __shfl_down(v, off, 64);
    if (px == 0) partial[blockIdx.x] = v;
  }
}

// ---------------- kernel 5: final deterministic reduction (1024 partials) ----------------
__global__ __launch_bounds__(256) void k_final(const float* __restrict__ partial,
                                               float* __restrict__ out) {
  int t = threadIdx.x;
  float v = partial[t] + partial[256 + t] + partial[512 + t] + partial[768 + t];
#pragma unroll
  for (int off = 32; off > 0; off >>= 1) v += __shfl_down(v, off, 64);
  __shared__ float red[4];
  int wid = t >> 6, lane = t & 63;
  if (lane == 0) red[wid] = v;
  __syncthreads();
  if (t == 0) out[0] = (red[0] + red[1] + red[2] + red[3]) * (1.0f / (float)NBP);
}

// ---------------- launch ----------------
extern "C" void kernel_launch(void* const* d_in, const int* in_sizes, int n_in,
                              void* d_out, int out_size, void* d_ws, size_t ws_size,
                              hipStream_t stream) {
  const float* fS     = (const float*)d_in[0];
  const float* fT     = (const float*)d_in[1];
  const float* target = (const float*)d_in[2];
  char* ws = (char*)d_ws;
  // ws layout (bytes):
  u8*    lab     = (u8*)   (ws + 0);        // 65536
  int*   counts  = (int*)  (ws + 65536);    // 608 -> pad 66560
  float* sums    = (float*)(ws + 66560);    // 311296 -> 377856
  float* means   = (float*)(ws + 377856);   // 311296 -> 689152
  float* cnorm   = (float*)(ws + 689152);   // 1216 -> 690432
  float* partial = (float*)(ws + 690432);   // 4096 -> 694528
  float* gpart   = (float*)(ws + 694528);   // 32*16*2432*4 = 4980736 -> ~5.7 MB
  float* out = (float*)d_out;

  hipMemsetAsync(counts, 0, NB * NK * sizeof(int), stream);
  k_argmax<<<NBP / 256,   256, 0, stream>>>(target, lab, counts);
  k_gemm  <<<512,         512, 0, stream>>>(fS, fT, lab, gpart);
  k_sumred<<<32,          256, 0, stream>>>(gpart, sums);
  k_means <<<NB * NK,     256, 0, stream>>>(sums, counts, means, cnorm);
  k_cos   <<<NB * (NP / 64), 256, 0, stream>>>(fS, fT, lab, means, cnorm, partial);
  k_final <<<1, 256, 0, stream>>>(partial, out);
}